// Round 9
// baseline (35.707 us; speedup 1.0000x reference)
//
#include <hip/hip_runtime.h>
#include <hip/hip_bf16.h>

#define D 128
#define BLOCK 256
#define ROWS_PER_WAVE 16            // 8 KB of h per wave
#define CHUNKS (ROWS_PER_WAVE / 2)  // 1 KB (2 rows) per chunk

template <int CTRL>
__device__ __forceinline__ float dpp_add(float x) {
    int yi = __builtin_amdgcn_update_dpp(0, __float_as_int(x), CTRL, 0xF, 0xF, true);
    return x + __int_as_float(yi);
}

__device__ __forceinline__ float reduce32(float x) {
    x = dpp_add<0xB1>(x);    // quad_perm xor1
    x = dpp_add<0x4E>(x);    // quad_perm xor2
    x = dpp_add<0x141>(x);   // row_half_mirror
    x = dpp_add<0x140>(x);   // row_mirror
    int yi = __builtin_amdgcn_ds_swizzle(__float_as_int(x), 0x401F); // xor 16
    return x + __int_as_float(yi);
}

// Phase 1 with DIAGNOSTIC internal repeat: re-reads h and rewrites identical
// pu/pv `reps` times (idempotent, deterministic). reps=3 pushes this dispatch
// to ~46us so it finally appears above the harness fill kernels in the
// rocprof top-5, exposing hbm_gbps / FETCH_SIZE / VALUBusy for pure p1.
__global__ __launch_bounds__(BLOCK) void node_proj_kernel(
    const float* __restrict__ h,
    const float* __restrict__ W_w,
    float*       __restrict__ pu,
    float*       __restrict__ pv,
    int n_nodes, int reps)
{
    const int lane = threadIdx.x & 63;
    const int wave = (blockIdx.x * BLOCK + threadIdx.x) >> 6;
    const int pos  = lane & 31;
    const int half = lane >> 5;

    const float4 wu = reinterpret_cast<const float4*>(W_w)[pos];
    const float4 wv = reinterpret_cast<const float4*>(W_w)[32 + pos];

    const int nb = wave * ROWS_PER_WAVE;
    if (nb >= n_nodes) return;

    const float4* __restrict__ h4 = reinterpret_cast<const float4*>(h);

    if (nb + ROWS_PER_WAVE <= n_nodes) {
        for (int r = 0; r < reps; ++r) {
            int zoff = 0;
            asm volatile("" : "+v"(zoff));   // opaque 0: forces real re-load each rep
            const size_t base = (size_t)nb * 32 + lane + zoff;
            float4 x[CHUNKS];
#pragma unroll
            for (int c = 0; c < CHUNKS; ++c) x[c] = h4[base + (size_t)c * 64];

#pragma unroll
            for (int c = 0; c < CHUNKS; ++c) {
                float su = x[c].x * wu.x + x[c].y * wu.y + x[c].z * wu.z + x[c].w * wu.w;
                float sv = x[c].x * wv.x + x[c].y * wv.y + x[c].z * wv.z + x[c].w * wv.w;
                su = reduce32(su);
                sv = reduce32(sv);
                if (pos == 0) {
                    const int node = nb + c * 2 + half;
                    pu[node] = su;
                    pv[node] = sv;
                }
            }
        }
    } else {
        for (int c = 0; c < CHUNKS; ++c) {
            const int node = nb + c * 2 + half;
            if (node < n_nodes) {
                float4 x = h4[(size_t)node * 32 + pos];
                float su = x.x * wu.x + x.y * wu.y + x.z * wu.z + x.w * wu.w;
                float sv = x.x * wv.x + x.y * wv.y + x.z * wv.z + x.w * wv.w;
                su = reduce32(su);
                sv = reduce32(sv);
                if (pos == 0) { pu[node] = su; pv[node] = sv; }
            }
        }
    }
}

// Phase 2: unchanged (R3 version).
__global__ __launch_bounds__(BLOCK) void edge_score_kernel(
    const float* __restrict__ pu,
    const float* __restrict__ pv,
    const int*   __restrict__ src,
    const int*   __restrict__ dst,
    const float* __restrict__ W_b,
    float*       __restrict__ out,
    int n_edges)
{
    const float bias = W_b[0];
    const int n_quads = n_edges >> 2;
    const int q = blockIdx.x * BLOCK + threadIdx.x;

    if (q < n_quads) {
        int4 s = reinterpret_cast<const int4*>(src)[q];
        int4 d = reinterpret_cast<const int4*>(dst)[q];
        float4 r;
        r.x = pu[s.x] + pv[d.x] + bias;
        r.y = pu[s.y] + pv[d.y] + bias;
        r.z = pu[s.z] + pv[d.z] + bias;
        r.w = pu[s.w] + pv[d.w] + bias;
        reinterpret_cast<float4*>(out)[q] = r;
    }

    if (q == 0) {
        for (int e = n_quads << 2; e < n_edges; ++e)
            out[e] = pu[src[e]] + pv[dst[e]] + bias;
    }
}

extern "C" void kernel_launch(void* const* d_in, const int* in_sizes, int n_in,
                              void* d_out, int out_size, void* d_ws, size_t ws_size,
                              hipStream_t stream)
{
    const float* h   = (const float*)d_in[0];
    const int*   src = (const int*)d_in[1];
    const int*   dst = (const int*)d_in[2];
    const float* W_w = (const float*)d_in[3];
    const float* W_b = (const float*)d_in[4];
    float*       out = (float*)d_out;

    const int n_nodes = in_sizes[0] / D;   // 100000
    const int n_edges = in_sizes[1];       // 625000

    float* pu = (float*)d_ws;
    float* pv = pu + n_nodes;

    const int waves1  = (n_nodes + ROWS_PER_WAVE - 1) / ROWS_PER_WAVE;  // 6250
    const int blocks1 = (waves1 * 64 + BLOCK - 1) / BLOCK;              // 1563
    // DIAGNOSTIC: reps=3 -> dispatch ~46us, visible in rocprof top-5.
    node_proj_kernel<<<blocks1, BLOCK, 0, stream>>>(h, W_w, pu, pv, n_nodes, 3);

    const int n_quads = n_edges >> 2;                                   // 156250
    const int blocks2 = (n_quads + BLOCK - 1) / BLOCK;                  // 611
    edge_score_kernel<<<blocks2, BLOCK, 0, stream>>>(pu, pv, src, dst, W_b, out, n_edges);
}